// Round 2
// baseline (586.724 us; speedup 1.0000x reference)
//
#include <hip/hip_runtime.h>
#include <hip/hip_bf16.h>
#include <stdint.h>

// Problem constants: B=4, T=4096, L=4096, H=1024
#define BB 4
#define TT 4096
#define LL 4096
#define HH 1024

typedef __bf16 bf16x8 __attribute__((ext_vector_type(8)));
typedef float f32x4 __attribute__((ext_vector_type(4)));
typedef unsigned short us8v __attribute__((ext_vector_type(8)));

// f32 -> bf16 bits, round-to-nearest-even (inputs are normal floats, no NaN)
__device__ __forceinline__ unsigned short f2b(float f) {
    unsigned u = __builtin_bit_cast(unsigned, f);
    unsigned r = (u + 0x7FFFu + ((u >> 16) & 1u)) >> 16;
    return (unsigned short)r;
}
__device__ __forceinline__ float b2f(unsigned short u) {
    unsigned x = ((unsigned)u) << 16;
    return __builtin_bit_cast(float, x);
}

// async global->LDS, 16B per lane. LDS base must be wave-uniform (HW adds lane*16).
__device__ __forceinline__ void gload_lds16(const void* g, void* l) {
    __builtin_amdgcn_global_load_lds(
        (const __attribute__((address_space(1))) void*)(uintptr_t)g,
        (__attribute__((address_space(3))) void*)(uintptr_t)l,
        16, 0, 0);
}

// ---------------- f32 -> bf16 conversion (vectorized float4 -> ushort4) ----------------
__global__ __launch_bounds__(256) void cvt_f32_bf16_k(const float4* __restrict__ src,
                                                      ushort4* __restrict__ dst, int n4) {
    int i = blockIdx.x * 256 + threadIdx.x;
    if (i >= n4) return;
    float4 v = src[i];
    ushort4 o;
    o.x = f2b(v.x); o.y = f2b(v.y); o.z = f2b(v.z); o.w = f2b(v.w);
    dst[i] = o;
}

// ---------------- bf16 GEMM: C[M,N] = A[M,K] * Bw[N,K]^T  (both row-major along K) -----
// m97 structure: 128x128 tile, BK=32, 4 waves, each wave 64x64 (4x4 frags of 16x16x32)
template <int OUT_F32>
__global__ __launch_bounds__(256) void gemm_bt(const unsigned short* __restrict__ A,
                                               const unsigned short* __restrict__ Bw,
                                               void* __restrict__ Cout,
                                               int M, int N, int K,
                                               const float* __restrict__ scale_ptr) {
    constexpr int BK = 32;
    __shared__ unsigned short ldsA[128 * BK];
    __shared__ unsigned short ldsB[128 * BK];

    const int tid = threadIdx.x;
    const int wave = tid >> 6, lane = tid & 63;
    const int m0 = blockIdx.y * 128, n0 = blockIdx.x * 128;
    const int wr = wave >> 1, wc = wave & 1;

    f32x4 acc[4][4];
#pragma unroll
    for (int m = 0; m < 4; m++)
#pragma unroll
        for (int n = 0; n < 4; n++) acc[m][n] = (f32x4)(0.0f);

    const unsigned short* Ab = A + (size_t)m0 * K;
    const unsigned short* Bb = Bw + (size_t)n0 * K;
    // staging map: lane l of wave w writes LDS bytes [base + l*16); row-major [128][32]
    const int row0 = tid >> 2;           // (tid*16B)/64B-per-row
    const int col0 = (tid & 3) * 8;      // element offset in row

    for (int k0 = 0; k0 < K; k0 += BK) {
#pragma unroll
        for (int r = 0; r < 2; r++) {
            const int row = row0 + r * 64;
            gload_lds16(Ab + (size_t)row * K + k0 + col0, &ldsA[r * 2048 + wave * 512]);
            gload_lds16(Bb + (size_t)row * K + k0 + col0, &ldsB[r * 2048 + wave * 512]);
        }
        __syncthreads();

        bf16x8 af[4], bfr[4];
        const int lr = lane & 15;
        const int kc = (lane >> 4) * 8;
#pragma unroll
        for (int m = 0; m < 4; m++)
            af[m] = *reinterpret_cast<const bf16x8*>(&ldsA[(wr * 64 + m * 16 + lr) * BK + kc]);
#pragma unroll
        for (int n = 0; n < 4; n++)
            bfr[n] = *reinterpret_cast<const bf16x8*>(&ldsB[(wc * 64 + n * 16 + lr) * BK + kc]);
#pragma unroll
        for (int m = 0; m < 4; m++)
#pragma unroll
            for (int n = 0; n < 4; n++)
                acc[m][n] = __builtin_amdgcn_mfma_f32_16x16x32_bf16(af[m], bfr[n], acc[m][n], 0, 0, 0);
        __syncthreads();
    }

    const float s = scale_ptr ? *scale_ptr : 1.0f;
    const int cr = (lane >> 4) * 4, cc = lane & 15;
#pragma unroll
    for (int m = 0; m < 4; m++) {
#pragma unroll
        for (int n = 0; n < 4; n++) {
#pragma unroll
            for (int r = 0; r < 4; r++) {
                const int row = m0 + wr * 64 + m * 16 + cr + r;
                const int col = n0 + wc * 64 + n * 16 + cc;
                if (OUT_F32)
                    reinterpret_cast<float*>(Cout)[(size_t)row * N + col] = acc[m][n][r] * s;
                else
                    reinterpret_cast<unsigned short*>(Cout)[(size_t)row * N + col] = f2b(acc[m][n][r] * s);
            }
        }
    }
}

// ---------------- windowed 3-way gated attention (batch-local) ----------------
// Q:  [T][2048]  (qj | qi)   KV: [L][4096] (kj | vj | ki | vi)   one wave per t
__device__ __forceinline__ float wave_sum(float v) {
#pragma unroll
    for (int off = 32; off > 0; off >>= 1) v += __shfl_xor(v, off, 64);
    return v;
}

__global__ __launch_bounds__(256) void attn_k(const unsigned short* __restrict__ Q,
                                              const unsigned short* __restrict__ KV,
                                              const int* __restrict__ adv_ids,   // [L] batch-local
                                              const int* __restrict__ ptr_ids,   // [T] batch-local
                                              const float* __restrict__ council,
                                              unsigned short* __restrict__ ctx) {
    const int wave = threadIdx.x >> 6, lane = threadIdx.x & 63;
    const int t = blockIdx.x * 4 + wave;     // 0 .. T-1

    const int p = ptr_ids[t];
    int idx[3];
#pragma unroll
    for (int w = 0; w < 3; w++) {
        int v = p + w;
        idx[w] = v < (LL - 1) ? v : (LL - 1);
        if (idx[w] < 0) idx[w] = 0;
    }
    const int rel = adv_ids[idx[0]];

    const unsigned short* qrow = Q + (size_t)t * 2048 + lane * 16;
    us8v qj0 = *reinterpret_cast<const us8v*>(qrow);
    us8v qj1 = *reinterpret_cast<const us8v*>(qrow + 8);
    us8v qi0 = *reinterpret_cast<const us8v*>(qrow + 1024);
    us8v qi1 = *reinterpret_cast<const us8v*>(qrow + 1032);

    float sj[3], si[3];
    us8v vj[3][2], vi[3][2];
#pragma unroll
    for (int w = 0; w < 3; w++) {
        const unsigned short* kvrow = KV + (size_t)idx[w] * 4096 + lane * 16;
        us8v kj0 = *reinterpret_cast<const us8v*>(kvrow);
        us8v kj1 = *reinterpret_cast<const us8v*>(kvrow + 8);
        vj[w][0] = *reinterpret_cast<const us8v*>(kvrow + 1024);
        vj[w][1] = *reinterpret_cast<const us8v*>(kvrow + 1032);
        us8v ki0 = *reinterpret_cast<const us8v*>(kvrow + 2048);
        us8v ki1 = *reinterpret_cast<const us8v*>(kvrow + 2056);
        vi[w][0] = *reinterpret_cast<const us8v*>(kvrow + 3072);
        vi[w][1] = *reinterpret_cast<const us8v*>(kvrow + 3080);

        float dj = 0.f, di = 0.f;
#pragma unroll
        for (int e = 0; e < 8; e++) {
            dj += b2f(qj0[e]) * b2f(kj0[e]);
            dj += b2f(qj1[e]) * b2f(kj1[e]);
            di += b2f(qi0[e]) * b2f(ki0[e]);
            di += b2f(qi1[e]) * b2f(ki1[e]);
        }
        sj[w] = wave_sum(dj) * 0.03125f;   // 1/sqrt(1024)
        si[w] = wave_sum(di) * 0.03125f;
    }

    const float l1 = sj[1], l2 = sj[2];
    float lf;
    switch (rel) {
        case 0: lf = l1 + l2; break;
        case 1: lf = fmaxf(l1, l2); break;
        case 2: lf = -l1; break;
        case 3: lf = fmaxf(-l1, l2); break;
        case 4: lf = fabsf(l1 - l2); break;
        default: lf = sj[0]; break;
    }

    float mj = fmaxf(lf, fmaxf(l1, l2));
    float ej0 = expf(lf - mj), ej1 = expf(l1 - mj), ej2 = expf(l2 - mj);
    float invj = 1.0f / (ej0 + ej1 + ej2);
    float aj0 = ej0 * invj, aj1 = ej1 * invj, aj2 = ej2 * invj;

    float mi = fmaxf(si[0], fmaxf(si[1], si[2]));
    float ei0 = expf(si[0] - mi), ei1 = expf(si[1] - mi), ei2 = expf(si[2] - mi);
    float invi = 1.0f / (ei0 + ei1 + ei2);
    float ai0 = ei0 * invi, ai1 = ei1 * invi, ai2 = ei2 * invi;

    float c0 = council[0], c1 = council[1];
    float cm = fmaxf(c0, c1);
    float w0 = expf(c0 - cm), w1 = expf(c1 - cm);
    float wsum = 1.0f / (w0 + w1);
    w0 *= wsum; w1 *= wsum;

    us8v outv[2];
#pragma unroll
    for (int h = 0; h < 2; h++) {
#pragma unroll
        for (int e = 0; e < 8; e++) {
            float cj = aj0 * b2f(vj[0][h][e]) + aj1 * b2f(vj[1][h][e]) + aj2 * b2f(vj[2][h][e]);
            float ci = ai0 * b2f(vi[0][h][e]) + ai1 * b2f(vi[1][h][e]) + ai2 * b2f(vi[2][h][e]);
            outv[h][e] = f2b(w0 * cj + w1 * ci);
        }
    }
    unsigned short* dst = ctx + (size_t)t * 1024 + lane * 16;
    *reinterpret_cast<us8v*>(dst) = outv[0];
    *reinterpret_cast<us8v*>(dst + 8) = outv[1];
}

// ---------------- launch ----------------
extern "C" void kernel_launch(void* const* d_in, const int* in_sizes, int n_in,
                              void* d_out, int out_size, void* d_ws, size_t ws_size,
                              hipStream_t stream) {
    const float* hs      = (const float*)d_in[0];
    const float* adv     = (const float*)d_in[1];
    const int*   adv_ids = (const int*)d_in[2];
    const int*   ptr_ids = (const int*)d_in[3];
    const float* Wqj = (const float*)d_in[4];
    const float* Wkj = (const float*)d_in[5];
    const float* Wvj = (const float*)d_in[6];
    const float* Wqi = (const float*)d_in[7];
    const float* Wki = (const float*)d_in[8];
    const float* Wvi = (const float*)d_in[9];
    const float* Wout = (const float*)d_in[10];
    const float* gain = (const float*)d_in[11];
    const float* council = (const float*)d_in[12];
    float* out = (float*)d_out;

    const size_t WN  = (size_t)HH * HH;          // 1,048,576 per weight matrix
    const size_t NHb = (size_t)TT * HH;          // 4,194,304 per batch (hs/adv/out)
    dim3 blk(256);

    auto cvt = [&](const float* s, unsigned short* d, size_t n) {
        int n4 = (int)(n / 4);
        cvt_f32_bf16_k<<<dim3(n4 / 256), blk, 0, stream>>>((const float4*)s, (ushort4*)d, n4);
    };

    // ---- weight buffers (always resident): 14.7 MB ----
    char* ws = (char*)d_ws;
    unsigned short* Wq  = (unsigned short*)ws;  ws += WN * 2 * 2;   // [2048][1024]
    unsigned short* Wkv = (unsigned short*)ws;  ws += WN * 4 * 2;   // [4096][1024]
    unsigned short* Wo  = (unsigned short*)ws;  ws += WN * 2;       // [1024][1024]

    cvt(Wqj, Wq, WN);
    cvt(Wqi, Wq + WN, WN);
    cvt(Wkj, Wkv, WN);
    cvt(Wvj, Wkv + WN, WN);
    cvt(Wki, Wkv + 2 * WN, WN);
    cvt(Wvi, Wkv + 3 * WN, WN);
    cvt(Wout, Wo, WN);

    const size_t wbytes = (WN * 2 + WN * 4 + WN) * 2;                       // 14,680,064
    const size_t full_need  = wbytes + (NHb * BB) * 2 * 2                   // hsb+advb full
                            + (size_t)16384 * 2048 * 2                      // Qb
                            + (size_t)16384 * 4096 * 2                      // KVb
                            + (size_t)16384 * 1024 * 2;                     // ctx  = 316.7 MB

    if (ws_size >= full_need) {
        // ---- full-size path (fewer launches, bigger grids) ----
        unsigned short* hsb  = (unsigned short*)ws;  ws += NHb * BB * 2;
        unsigned short* advb = (unsigned short*)ws;  ws += NHb * BB * 2;
        unsigned short* Qb   = (unsigned short*)ws;  ws += (size_t)16384 * 2048 * 2;
        unsigned short* KVb  = (unsigned short*)ws;  ws += (size_t)16384 * 4096 * 2;
        unsigned short* ctx  = (unsigned short*)ws;

        cvt(hs, hsb, NHb * BB);
        cvt(adv, advb, NHb * BB);
        gemm_bt<0><<<dim3(16, 128), blk, 0, stream>>>(hsb, Wq, Qb, 16384, 2048, 1024, nullptr);
        gemm_bt<0><<<dim3(32, 128), blk, 0, stream>>>(advb, Wkv, KVb, 16384, 4096, 1024, nullptr);
        for (int b = 0; b < BB; b++)
            attn_k<<<dim3(TT / 4), blk, 0, stream>>>(Qb + (size_t)b * TT * 2048,
                                                     KVb + (size_t)b * LL * 4096,
                                                     adv_ids + b * LL, ptr_ids + b * TT,
                                                     council, ctx + (size_t)b * TT * 1024);
        gemm_bt<1><<<dim3(8, 128), blk, 0, stream>>>(ctx, Wo, out, 16384, 1024, 1024, gain);
    } else {
        // ---- batch-chunked path: peak 90.2 MB of d_ws ----
        unsigned short* hsb  = (unsigned short*)ws;  ws += NHb * 2;                 // 8.4 MB
        unsigned short* advb = (unsigned short*)ws;  ws += NHb * 2;                 // 8.4 MB
        unsigned short* Qb   = (unsigned short*)ws;  ws += (size_t)TT * 2048 * 2;   // 16.8 MB
        unsigned short* KVb  = (unsigned short*)ws;  ws += (size_t)LL * 4096 * 2;   // 33.6 MB
        unsigned short* ctx  = (unsigned short*)ws;                                  // 8.4 MB

        for (int b = 0; b < BB; b++) {
            cvt(hs + (size_t)b * NHb, hsb, NHb);
            cvt(adv + (size_t)b * NHb, advb, NHb);
            gemm_bt<0><<<dim3(16, 32), blk, 0, stream>>>(hsb, Wq, Qb, TT, 2048, 1024, nullptr);
            gemm_bt<0><<<dim3(32, 32), blk, 0, stream>>>(advb, Wkv, KVb, LL, 4096, 1024, nullptr);
            attn_k<<<dim3(TT / 4), blk, 0, stream>>>(Qb, KVb, adv_ids + b * LL,
                                                     ptr_ids + b * TT, council, ctx);
            gemm_bt<1><<<dim3(8, 32), blk, 0, stream>>>(ctx, Wo, out + (size_t)b * NHb,
                                                        TT, 1024, 1024, gain);
        }
    }
}

// Round 3
// 420.817 us; speedup vs baseline: 1.3942x; 1.3942x over previous
//
#include <hip/hip_runtime.h>
#include <hip/hip_bf16.h>
#include <stdint.h>

// Problem constants: B=4, T=4096, L=4096, H=1024
#define BB 4
#define TT 4096
#define LL 4096
#define HH 1024

typedef __bf16 bf16x8 __attribute__((ext_vector_type(8)));
typedef float f32x4 __attribute__((ext_vector_type(4)));
typedef unsigned short us8v __attribute__((ext_vector_type(8)));

// f32 -> bf16 bits, round-to-nearest-even
__device__ __forceinline__ unsigned short f2b(float f) {
    unsigned u = __builtin_bit_cast(unsigned, f);
    unsigned r = (u + 0x7FFFu + ((u >> 16) & 1u)) >> 16;
    return (unsigned short)r;
}
__device__ __forceinline__ float b2f(unsigned short u) {
    unsigned x = ((unsigned)u) << 16;
    return __builtin_bit_cast(float, x);
}

// async global->LDS, 16B/lane. LDS base wave-uniform (HW adds lane*16).
__device__ __forceinline__ void gload_lds16(const void* g, void* l) {
    __builtin_amdgcn_global_load_lds(
        (const __attribute__((address_space(1))) void*)(uintptr_t)g,
        (__attribute__((address_space(3))) void*)(uintptr_t)l,
        16, 0, 0);
}

// ---------------- f32 -> bf16 conversion ----------------
__global__ __launch_bounds__(256) void cvt_f32_bf16_k(const float4* __restrict__ src,
                                                      ushort4* __restrict__ dst, int n4) {
    int i = blockIdx.x * 256 + threadIdx.x;
    if (i >= n4) return;
    float4 v = src[i];
    ushort4 o;
    o.x = f2b(v.x); o.y = f2b(v.y); o.z = f2b(v.z); o.w = f2b(v.w);
    dst[i] = o;
}

// ---------------- f32 [1024][1024] -> bf16 transpose ----------------
__global__ __launch_bounds__(256) void transp_cvt_k(const float* __restrict__ src,
                                                    unsigned short* __restrict__ dst) {
    __shared__ float tile[32][33];
    const int lx = threadIdx.x & 31, ly = threadIdx.x >> 5;  // ly 0..7
    const int R = blockIdx.y * 32, C = blockIdx.x * 32;
#pragma unroll
    for (int rr = 0; rr < 4; rr++)
        tile[ly + rr * 8][lx] = src[(size_t)(R + ly + rr * 8) * HH + C + lx];
    __syncthreads();
#pragma unroll
    for (int rr = 0; rr < 4; rr++)
        dst[(size_t)(C + ly + rr * 8) * HH + R + lx] = f2b(tile[lx][ly + rr * 8]);
}

// ---------------- bf16 GEMM: C[M,N] = A[M,K] * Bw[N,K]^T, bf16 out --------------------
// 128x128 tile, BK=64, 4 waves (2x2 of 64x64), 32 MFMA per barrier pair.
// LDS tiles [128][64] with XOR bank-swizzle: phys colbyte = log colbyte ^ ((row&7)<<4).
// global_load_lds writes linearly; the source column is pre-swizzled per lane (m173).
__global__ __launch_bounds__(256) void gemm_bt(const unsigned short* __restrict__ A,
                                               const unsigned short* __restrict__ Bw,
                                               unsigned short* __restrict__ C,
                                               int M, int N, int K) {
    __shared__ unsigned short ldsA[128 * 64];   // 16 KB
    __shared__ unsigned short ldsB[128 * 64];   // 16 KB

    const int tid = threadIdx.x;
    const int wave = tid >> 6, lane = tid & 63;
    const int m0 = blockIdx.y * 128, n0 = blockIdx.x * 128;
    const int wr = wave >> 1, wc = wave & 1;

    f32x4 acc[4][4];
#pragma unroll
    for (int m = 0; m < 4; m++)
#pragma unroll
        for (int n = 0; n < 4; n++) acc[m][n] = (f32x4)(0.0f);

    const unsigned short* Ab = A + (size_t)m0 * K;
    const unsigned short* Bb = Bw + (size_t)n0 * K;
    // staging: thread tid covers LDS bytes [r*4096 + tid*16); row = r*32 + tid/8 (128B rows)
    // phys colbyte = (tid&7)*16  ->  logical col = phys ^ ((row&7)<<4); row&7 = (tid>>3)&7
    const int rbase = tid >> 3;                              // 0..31
    const int col0 = (((tid & 7) ^ (rbase & 7)) << 3);       // element col (swizzled source)

    for (int k0 = 0; k0 < K; k0 += 64) {
#pragma unroll
        for (int r = 0; r < 4; r++) {
            const int row = r * 32 + rbase;
            gload_lds16(Ab + (size_t)row * K + k0 + col0, &ldsA[r * 2048 + wave * 512]);
            gload_lds16(Bb + (size_t)row * K + k0 + col0, &ldsB[r * 2048 + wave * 512]);
        }
        __syncthreads();

        const int lr = lane & 15, hi = lane >> 4;
        const int sw = (lr & 7) << 4;                        // row-dependent XOR (bytes)
        const int c0 = ((hi * 16) ^ sw) >> 1;                // kk=0 slice, elements
        const int c1 = ((64 + hi * 16) ^ sw) >> 1;           // kk=1 slice
        bf16x8 a0[4], a1[4], b0[4], b1[4];
#pragma unroll
        for (int m = 0; m < 4; m++) {
            const int row = (wr * 64 + m * 16 + lr) * 64;
            a0[m] = *reinterpret_cast<const bf16x8*>(&ldsA[row + c0]);
            a1[m] = *reinterpret_cast<const bf16x8*>(&ldsA[row + c1]);
        }
#pragma unroll
        for (int n = 0; n < 4; n++) {
            const int row = (wc * 64 + n * 16 + lr) * 64;
            b0[n] = *reinterpret_cast<const bf16x8*>(&ldsB[row + c0]);
            b1[n] = *reinterpret_cast<const bf16x8*>(&ldsB[row + c1]);
        }
#pragma unroll
        for (int m = 0; m < 4; m++)
#pragma unroll
            for (int n = 0; n < 4; n++)
                acc[m][n] = __builtin_amdgcn_mfma_f32_16x16x32_bf16(a0[m], b0[n], acc[m][n], 0, 0, 0);
#pragma unroll
        for (int m = 0; m < 4; m++)
#pragma unroll
            for (int n = 0; n < 4; n++)
                acc[m][n] = __builtin_amdgcn_mfma_f32_16x16x32_bf16(a1[m], b1[n], acc[m][n], 0, 0, 0);
        __syncthreads();
    }

    const int cc = lane & 15, cr = (lane >> 4) * 4;
#pragma unroll
    for (int m = 0; m < 4; m++)
#pragma unroll
        for (int n = 0; n < 4; n++)
#pragma unroll
            for (int r = 0; r < 4; r++) {
                const int row = m0 + wr * 64 + m * 16 + cr + r;
                const int col = n0 + wc * 64 + n * 16 + cc;
                C[(size_t)row * N + col] = f2b(acc[m][n][r]);
            }
}

// ---------------- windowed 3-way gated attention (batch-local, fused output) ----------
// Q: [T][2048] (qj|qi)   KV: [L][4096] (kj | vj' | ki | vi')  with v' = v @ Wout^T folded
// one wave per t; writes final f32 output row (x gain) directly.
__device__ __forceinline__ float wave_sum(float v) {
#pragma unroll
    for (int off = 32; off > 0; off >>= 1) v += __shfl_xor(v, off, 64);
    return v;
}

__global__ __launch_bounds__(256) void attn_k(const unsigned short* __restrict__ Q,
                                              const unsigned short* __restrict__ KV,
                                              const int* __restrict__ adv_ids,   // [L]
                                              const int* __restrict__ ptr_ids,   // [T]
                                              const float* __restrict__ council,
                                              const float* __restrict__ gain_p,
                                              float* __restrict__ out) {
    const int wave = threadIdx.x >> 6, lane = threadIdx.x & 63;
    const int t = blockIdx.x * 4 + wave;

    const int p = ptr_ids[t];
    int idx[3];
#pragma unroll
    for (int w = 0; w < 3; w++) {
        int v = p + w;
        idx[w] = v < (LL - 1) ? v : (LL - 1);
        if (idx[w] < 0) idx[w] = 0;
    }
    const int rel = adv_ids[idx[0]];

    const unsigned short* qrow = Q + (size_t)t * 2048 + lane * 16;
    us8v qj0 = *reinterpret_cast<const us8v*>(qrow);
    us8v qj1 = *reinterpret_cast<const us8v*>(qrow + 8);
    us8v qi0 = *reinterpret_cast<const us8v*>(qrow + 1024);
    us8v qi1 = *reinterpret_cast<const us8v*>(qrow + 1032);

    float sj[3], si[3];
    us8v vj[3][2], vi[3][2];
#pragma unroll
    for (int w = 0; w < 3; w++) {
        const unsigned short* kvrow = KV + (size_t)idx[w] * 4096 + lane * 16;
        us8v kj0 = *reinterpret_cast<const us8v*>(kvrow);
        us8v kj1 = *reinterpret_cast<const us8v*>(kvrow + 8);
        vj[w][0] = *reinterpret_cast<const us8v*>(kvrow + 1024);
        vj[w][1] = *reinterpret_cast<const us8v*>(kvrow + 1032);
        us8v ki0 = *reinterpret_cast<const us8v*>(kvrow + 2048);
        us8v ki1 = *reinterpret_cast<const us8v*>(kvrow + 2056);
        vi[w][0] = *reinterpret_cast<const us8v*>(kvrow + 3072);
        vi[w][1] = *reinterpret_cast<const us8v*>(kvrow + 3080);

        float dj = 0.f, di = 0.f;
#pragma unroll
        for (int e = 0; e < 8; e++) {
            dj += b2f(qj0[e]) * b2f(kj0[e]);
            dj += b2f(qj1[e]) * b2f(kj1[e]);
            di += b2f(qi0[e]) * b2f(ki0[e]);
            di += b2f(qi1[e]) * b2f(ki1[e]);
        }
        sj[w] = wave_sum(dj) * 0.03125f;   // 1/sqrt(1024)
        si[w] = wave_sum(di) * 0.03125f;
    }

    const float l1 = sj[1], l2 = sj[2];
    float lf;
    switch (rel) {
        case 0: lf = l1 + l2; break;
        case 1: lf = fmaxf(l1, l2); break;
        case 2: lf = -l1; break;
        case 3: lf = fmaxf(-l1, l2); break;
        case 4: lf = fabsf(l1 - l2); break;
        default: lf = sj[0]; break;
    }

    float mj = fmaxf(lf, fmaxf(l1, l2));
    float ej0 = expf(lf - mj), ej1 = expf(l1 - mj), ej2 = expf(l2 - mj);
    float invj = 1.0f / (ej0 + ej1 + ej2);
    float aj0 = ej0 * invj, aj1 = ej1 * invj, aj2 = ej2 * invj;

    float mi = fmaxf(si[0], fmaxf(si[1], si[2]));
    float ei0 = expf(si[0] - mi), ei1 = expf(si[1] - mi), ei2 = expf(si[2] - mi);
    float invi = 1.0f / (ei0 + ei1 + ei2);
    float ai0 = ei0 * invi, ai1 = ei1 * invi, ai2 = ei2 * invi;

    float c0 = council[0], c1 = council[1];
    float cm = fmaxf(c0, c1);
    float w0 = expf(c0 - cm), w1 = expf(c1 - cm);
    float wsum = 1.0f / (w0 + w1);
    w0 *= wsum; w1 *= wsum;
    const float g = *gain_p;

    float* dst = out + (size_t)t * 1024 + lane * 16;
#pragma unroll
    for (int h = 0; h < 2; h++) {
        float4 o0, o1;
        float* op[2] = {&o0.x, &o1.x};
#pragma unroll
        for (int e = 0; e < 8; e++) {
            float cj = aj0 * b2f(vj[0][h][e]) + aj1 * b2f(vj[1][h][e]) + aj2 * b2f(vj[2][h][e]);
            float ci = ai0 * b2f(vi[0][h][e]) + ai1 * b2f(vi[1][h][e]) + ai2 * b2f(vi[2][h][e]);
            op[e >> 2][e & 3] = (w0 * cj + w1 * ci) * g;
        }
        reinterpret_cast<float4*>(dst + h * 8)[0] = o0;
        reinterpret_cast<float4*>(dst + h * 8)[1] = o1;
    }
}

// ---------------- launch ----------------
extern "C" void kernel_launch(void* const* d_in, const int* in_sizes, int n_in,
                              void* d_out, int out_size, void* d_ws, size_t ws_size,
                              hipStream_t stream) {
    const float* hs      = (const float*)d_in[0];
    const float* adv     = (const float*)d_in[1];
    const int*   adv_ids = (const int*)d_in[2];
    const int*   ptr_ids = (const int*)d_in[3];
    const float* Wqj = (const float*)d_in[4];
    const float* Wkj = (const float*)d_in[5];
    const float* Wvj = (const float*)d_in[6];
    const float* Wqi = (const float*)d_in[7];
    const float* Wki = (const float*)d_in[8];
    const float* Wvi = (const float*)d_in[9];
    const float* Wout = (const float*)d_in[10];
    const float* gain = (const float*)d_in[11];
    const float* council = (const float*)d_in[12];
    float* out = (float*)d_out;

    const size_t WN  = (size_t)HH * HH;          // 1M elems per weight matrix
    const size_t NHb = (size_t)TT * HH;          // 4M elems per batch
    dim3 blk(256);

    auto cvt = [&](const float* s, unsigned short* d, size_t n) {
        int n4 = (int)(n / 4);
        cvt_f32_bf16_k<<<dim3(n4 / 256), blk, 0, stream>>>((const float4*)s, (ushort4*)d, n4);
    };

    // ---- weight buffers: 18 MB ----
    char* ws = (char*)d_ws;
    unsigned short* Wq    = (unsigned short*)ws;  ws += WN * 2 * 2;   // [2048][1024]
    unsigned short* Wkv   = (unsigned short*)ws;  ws += WN * 4 * 2;   // [kj|vj2|ki|vi2][1024]
    unsigned short* WoutB = (unsigned short*)ws;  ws += WN * 2;
    unsigned short* WvjT  = (unsigned short*)ws;  ws += WN * 2;
    unsigned short* WviT  = (unsigned short*)ws;  ws += WN * 2;

    cvt(Wqj, Wq, WN);
    cvt(Wqi, Wq + WN, WN);
    cvt(Wkj, Wkv, WN);
    cvt(Wki, Wkv + 2 * WN, WN);
    cvt(Wout, WoutB, WN);
    transp_cvt_k<<<dim3(32, 32), blk, 0, stream>>>(Wvj, WvjT);
    transp_cvt_k<<<dim3(32, 32), blk, 0, stream>>>(Wvi, WviT);
    // fold: Wv2[r][c] = sum_k Wout[r][k] * Wv[k][c]   (bf16 out, straight into KV pack)
    gemm_bt<<<dim3(8, 8), blk, 0, stream>>>(WoutB, WvjT, Wkv + WN, HH, HH, HH);
    gemm_bt<<<dim3(8, 8), blk, 0, stream>>>(WoutB, WviT, Wkv + 3 * WN, HH, HH, HH);

    // full path: advb 32MB + Qb 64MB + KVb 128MB (hsb 32MB aliased at KVb start,
    // consumed by Q-GEMM before KV-GEMM writes KVb — stream-ordered, safe)
    const size_t full_need = (size_t)(18 * 1024 * 1024) + (NHb * BB) * 2
                           + (size_t)16384 * 2048 * 2 + (size_t)16384 * 4096 * 2;

    if (ws_size >= full_need) {
        unsigned short* advb = (unsigned short*)ws;  ws += NHb * BB * 2;
        unsigned short* Qb   = (unsigned short*)ws;  ws += (size_t)16384 * 2048 * 2;
        unsigned short* KVb  = (unsigned short*)ws;
        unsigned short* hsb  = KVb;                   // aliased (see above)

        cvt(hs, hsb, NHb * BB);
        cvt(adv, advb, NHb * BB);
        gemm_bt<<<dim3(16, 128), blk, 0, stream>>>(hsb, Wq, Qb, 16384, 2048, 1024);
        gemm_bt<<<dim3(32, 128), blk, 0, stream>>>(advb, Wkv, KVb, 16384, 4096, 1024);
        for (int b = 0; b < BB; b++)
            attn_k<<<dim3(TT / 4), blk, 0, stream>>>(Qb + (size_t)b * TT * 2048,
                                                     KVb + (size_t)b * LL * 4096,
                                                     adv_ids + b * LL, ptr_ids + b * TT,
                                                     council, gain, out + (size_t)b * NHb);
    } else {
        // chunked per batch: advb 8MB + Qb 16MB + KVb 32MB (hsb aliased) = 74MB total
        unsigned short* advb = (unsigned short*)ws;  ws += NHb * 2;
        unsigned short* Qb   = (unsigned short*)ws;  ws += (size_t)TT * 2048 * 2;
        unsigned short* KVb  = (unsigned short*)ws;
        unsigned short* hsb  = KVb;                   // aliased

        for (int b = 0; b < BB; b++) {
            cvt(hs + (size_t)b * NHb, hsb, NHb);
            cvt(adv + (size_t)b * NHb, advb, NHb);
            gemm_bt<<<dim3(16, 32), blk, 0, stream>>>(hsb, Wq, Qb, TT, 2048, 1024);
            gemm_bt<<<dim3(32, 32), blk, 0, stream>>>(advb, Wkv, KVb, LL, 4096, 1024);
            attn_k<<<dim3(TT / 4), blk, 0, stream>>>(Qb, KVb, adv_ids + b * LL,
                                                     ptr_ids + b * TT, council, gain,
                                                     out + (size_t)b * NHb);
        }
    }
}

// Round 4
// 401.520 us; speedup vs baseline: 1.4613x; 1.0481x over previous
//
#include <hip/hip_runtime.h>
#include <hip/hip_bf16.h>
#include <stdint.h>

// Problem constants: B=4, T=4096, L=4096, H=1024
#define BB 4
#define TT 4096
#define LL 4096
#define HH 1024

typedef __bf16 bf16x8 __attribute__((ext_vector_type(8)));
typedef float f32x4 __attribute__((ext_vector_type(4)));
typedef unsigned short us8v __attribute__((ext_vector_type(8)));
typedef unsigned short us;

// f32 -> bf16 bits, round-to-nearest-even
__device__ __forceinline__ unsigned short f2b(float f) {
    unsigned u = __builtin_bit_cast(unsigned, f);
    unsigned r = (u + 0x7FFFu + ((u >> 16) & 1u)) >> 16;
    return (unsigned short)r;
}
__device__ __forceinline__ float b2f(unsigned short u) {
    unsigned x = ((unsigned)u) << 16;
    return __builtin_bit_cast(float, x);
}

// async global->LDS, 16B/lane. LDS base wave-uniform (HW adds lane*16).
__device__ __forceinline__ void gload_lds16(const void* g, void* l) {
    __builtin_amdgcn_global_load_lds(
        (const __attribute__((address_space(1))) void*)(uintptr_t)g,
        (__attribute__((address_space(3))) void*)(uintptr_t)l,
        16, 0, 0);
}

// ---------------- f32 -> bf16 conversion ----------------
__global__ __launch_bounds__(256) void cvt_f32_bf16_k(const float4* __restrict__ src,
                                                      ushort4* __restrict__ dst, int n4) {
    int i = blockIdx.x * 256 + threadIdx.x;
    if (i >= n4) return;
    float4 v = src[i];
    ushort4 o;
    o.x = f2b(v.x); o.y = f2b(v.y); o.z = f2b(v.z); o.w = f2b(v.w);
    dst[i] = o;
}

// ---------------- f32 [1024][1024] -> bf16 transpose ----------------
__global__ __launch_bounds__(256) void transp_cvt_k(const float* __restrict__ src,
                                                    unsigned short* __restrict__ dst) {
    __shared__ float tile[32][33];
    const int lx = threadIdx.x & 31, ly = threadIdx.x >> 5;
    const int R = blockIdx.y * 32, C = blockIdx.x * 32;
#pragma unroll
    for (int rr = 0; rr < 4; rr++)
        tile[ly + rr * 8][lx] = src[(size_t)(R + ly + rr * 8) * HH + C + lx];
    __syncthreads();
#pragma unroll
    for (int rr = 0; rr < 4; rr++)
        dst[(size_t)(C + ly + rr * 8) * HH + R + lx] = f2b(tile[lx][ly + rr * 8]);
}

// ---------------- small bf16 GEMM (128x128, 2-barrier) for weight folds -------------
__global__ __launch_bounds__(256) void gemm_bt(const unsigned short* __restrict__ A,
                                               const unsigned short* __restrict__ Bw,
                                               unsigned short* __restrict__ C,
                                               int M, int N, int K) {
    __shared__ unsigned short ldsA[128 * 64];
    __shared__ unsigned short ldsB[128 * 64];

    const int tid = threadIdx.x;
    const int wave = tid >> 6, lane = tid & 63;
    const int m0 = blockIdx.y * 128, n0 = blockIdx.x * 128;
    const int wr = wave >> 1, wc = wave & 1;

    f32x4 acc[4][4];
#pragma unroll
    for (int m = 0; m < 4; m++)
#pragma unroll
        for (int n = 0; n < 4; n++) acc[m][n] = (f32x4)(0.0f);

    const unsigned short* Ab = A + (size_t)m0 * K;
    const unsigned short* Bb = Bw + (size_t)n0 * K;
    const int rbase = tid >> 3;
    const int col0 = (((tid & 7) ^ (rbase & 7)) << 3);

    for (int k0 = 0; k0 < K; k0 += 64) {
#pragma unroll
        for (int r = 0; r < 4; r++) {
            const int row = r * 32 + rbase;
            gload_lds16(Ab + (size_t)row * K + k0 + col0, &ldsA[r * 2048 + wave * 512]);
            gload_lds16(Bb + (size_t)row * K + k0 + col0, &ldsB[r * 2048 + wave * 512]);
        }
        __syncthreads();

        const int lr = lane & 15, hi = lane >> 4;
        const int sw = (lr & 7) << 4;
        const int c0 = ((hi * 16) ^ sw) >> 1;
        const int c1 = ((64 + hi * 16) ^ sw) >> 1;
        bf16x8 a0[4], a1[4], b0[4], b1[4];
#pragma unroll
        for (int m = 0; m < 4; m++) {
            const int row = (wr * 64 + m * 16 + lr) * 64;
            a0[m] = *reinterpret_cast<const bf16x8*>(&ldsA[row + c0]);
            a1[m] = *reinterpret_cast<const bf16x8*>(&ldsA[row + c1]);
        }
#pragma unroll
        for (int n = 0; n < 4; n++) {
            const int row = (wc * 64 + n * 16 + lr) * 64;
            b0[n] = *reinterpret_cast<const bf16x8*>(&ldsB[row + c0]);
            b1[n] = *reinterpret_cast<const bf16x8*>(&ldsB[row + c1]);
        }
#pragma unroll
        for (int m = 0; m < 4; m++)
#pragma unroll
            for (int n = 0; n < 4; n++)
                acc[m][n] = __builtin_amdgcn_mfma_f32_16x16x32_bf16(a0[m], b0[n], acc[m][n], 0, 0, 0);
#pragma unroll
        for (int m = 0; m < 4; m++)
#pragma unroll
            for (int n = 0; n < 4; n++)
                acc[m][n] = __builtin_amdgcn_mfma_f32_16x16x32_bf16(a1[m], b1[n], acc[m][n], 0, 0, 0);
        __syncthreads();
    }

    const int cc = lane & 15, cr = (lane >> 4) * 4;
#pragma unroll
    for (int m = 0; m < 4; m++)
#pragma unroll
        for (int n = 0; n < 4; n++)
#pragma unroll
            for (int r = 0; r < 4; r++) {
                const int row = m0 + wr * 64 + m * 16 + cr + r;
                const int col = n0 + wc * 64 + n * 16 + cc;
                C[(size_t)row * N + col] = f2b(acc[m][n][r]);
            }
}

// ---------------- 256x256 8-phase GEMM: C[M,N] = A[M,K] * Bw[N,K]^T, bf16 out --------
// 8 waves (2M x 4N), per-wave 128x64 = 8x4 frags of 16x16x32. BK=64 split into two
// kk-chunks of 32; each chunk [256 rows][32 k] stored as 2-row/128B units with 8-slot
// XOR swizzle (slot ^= unit&7). Double-buffered (128 KiB). Counted vmcnt(4), never 0
// in the loop; setprio around MFMA clusters.
template<int MI0>
__device__ __forceinline__ void mfma_q(const bf16x8 a[4], const bf16x8 b[4], f32x4 acc[8][4]) {
    __builtin_amdgcn_s_setprio(1);
#pragma unroll
    for (int m = 0; m < 4; m++)
#pragma unroll
        for (int n = 0; n < 4; n++)
            acc[MI0 + m][n] = __builtin_amdgcn_mfma_f32_16x16x32_bf16(a[m], b[n], acc[MI0 + m][n], 0, 0, 0);
    __builtin_amdgcn_s_setprio(0);
}

#define STAGE2(chunk, src, kcol) \
    { _Pragma("unroll") for (int r_ = 0; r_ < 2; r_++) \
        gload_lds16((src) + (size_t)srow[r_] * K + (kcol) + scol[r_], (chunk) + r_ * 4096 + wave * 512); }

#define RD_A(cA, mi0) \
    { _Pragma("unroll") for (int m_ = 0; m_ < 4; m_++) \
        a[m_] = *reinterpret_cast<const bf16x8*>((cA) + offA + ((mi0) + m_) * 512); }

#define RD_B(cB) \
    { _Pragma("unroll") for (int n_ = 0; n_ < 4; n_++) \
        b[n_] = *reinterpret_cast<const bf16x8*>((cB) + offB + n_ * 512); }

#define BAR __builtin_amdgcn_s_barrier()
#define LGKM0 { asm volatile("s_waitcnt lgkmcnt(0)" ::: "memory"); __builtin_amdgcn_sched_barrier(0); }
#define VMW4 asm volatile("s_waitcnt vmcnt(4)" ::: "memory")
#define VMW0 asm volatile("s_waitcnt vmcnt(0)" ::: "memory")

// One K-tile (4 phases). STG: stage tile t+1 chunks. LAST: final tile (drain).
#define TILE8(cA0, cA1, cB0, cB1, nA0, nA1, nB0, nB1, knext, STG, LAST)     \
  {                                                                          \
    RD_A(cA0, 0); RD_B(cB0);                                                 \
    if (STG) STAGE2(nA0, Ablk, (knext));                                     \
    BAR; LGKM0; mfma_q<0>(a, b, acc);                                        \
    BAR;                                                                     \
    RD_A(cA0, 4);                                                            \
    if (STG) STAGE2(nB0, Bblk, (knext));                                     \
    BAR; LGKM0; mfma_q<4>(a, b, acc);                                        \
    if (LAST) { VMW0; } else { VMW4; }                                       \
    BAR;                                                                     \
    RD_A(cA1, 0); RD_B(cB1);                                                 \
    if (STG) STAGE2(nA1, Ablk, (knext) + 32);                                \
    BAR; LGKM0; mfma_q<0>(a, b, acc);                                        \
    BAR;                                                                     \
    RD_A(cA1, 4);                                                            \
    if (STG) STAGE2(nB1, Bblk, (knext) + 32);                                \
    BAR; LGKM0; mfma_q<4>(a, b, acc);                                        \
    if (STG) { VMW4; }                                                       \
    BAR;                                                                     \
  }

__global__ __launch_bounds__(512, 2) void gemm256(const us* __restrict__ A,
                                                  const us* __restrict__ Bw,
                                                  us* __restrict__ C,
                                                  int M, int N, int K, int gx) {
    __shared__ us lds[65536];   // 128 KB: buf0 {A0,A1,B0,B1}, buf1 {...}, 8192 elems each

    // bijective XCD swizzle (gridDim.x % 8 == 0 for all our launches)
    const int nwg = gridDim.x;
    const int bid = blockIdx.x;
    const int swz = (bid & 7) * (nwg >> 3) + (bid >> 3);
    const int bx = swz % gx, by = swz / gx;
    const int m0 = by * 256, n0 = bx * 256;

    const int tid = threadIdx.x;
    const int wave = tid >> 6, lane = tid & 63;
    const int wr = wave >> 2, wc = wave & 3;          // 2 x 4 waves
    const int lr = lane & 15, hi = lane >> 4;

    // stage source mapping: chunk byte = r*8192 + tid*16 -> unit q, slot p;
    // logical s = p ^ (q&7); row = 2q + s>>2; col = (s&3)*8
    int srow[2], scol[2];
#pragma unroll
    for (int r = 0; r < 2; r++) {
        const int q = r * 64 + (tid >> 3);
        const int s = (tid & 7) ^ (q & 7);
        srow[r] = 2 * q + (s >> 2);
        scol[r] = (s & 3) * 8;
    }
    const us* Ablk = A + (size_t)m0 * K;
    const us* Bblk = Bw + (size_t)n0 * K;

    // ds_read offsets (elems). frag i lives at off + i*512 (swizzle is frag-invariant:
    // row step 16 -> unit step 8 -> (q&7) unchanged).
    const int rA = wr * 128 + lr;
    const int offA = (rA >> 1) * 64 + (((((rA & 1) << 2) + hi) ^ ((rA >> 1) & 7)) << 3);
    const int rB = wc * 64 + lr;
    const int offB = (rB >> 1) * 64 + (((((rB & 1) << 2) + hi) ^ ((rB >> 1) & 7)) << 3);

    f32x4 acc[8][4];
#pragma unroll
    for (int m = 0; m < 8; m++)
#pragma unroll
        for (int n = 0; n < 4; n++) acc[m][n] = (f32x4)(0.0f);

    us* cA0 = lds;          us* cA1 = lds + 8192;
    us* cB0 = lds + 16384;  us* cB1 = lds + 24576;
    us* nA0 = lds + 32768;  us* nA1 = lds + 40960;
    us* nB0 = lds + 49152;  us* nB1 = lds + 57344;

    bf16x8 a[4], b[4];

    // prologue: stage tile 0 (order Akk0, Bkk0, Akk1, Bkk1)
    STAGE2(cA0, Ablk, 0);
    STAGE2(cB0, Bblk, 0);
    STAGE2(cA1, Ablk, 32);
    STAGE2(cB1, Bblk, 32);
    VMW4;
    BAR;

    const int NT = K >> 6;
    for (int t = 0; t < NT - 1; ++t) {
        const int knext = (t + 1) << 6;
        TILE8(cA0, cA1, cB0, cB1, nA0, nA1, nB0, nB1, knext, true, false);
        us* s0 = cA0; cA0 = nA0; nA0 = s0;
        us* s1 = cA1; cA1 = nA1; nA1 = s1;
        us* s2 = cB0; cB0 = nB0; nB0 = s2;
        us* s3 = cB1; cB1 = nB1; nB1 = s3;
    }
    TILE8(cA0, cA1, cB0, cB1, nA0, nA1, nB0, nB1, 0, false, true);

    // C write: col = lane&15, row = hi*4 + reg (verified layout)
    const int crow0 = m0 + wr * 128 + hi * 4;
    const int ccol0 = n0 + wc * 64 + lr;
#pragma unroll
    for (int mi = 0; mi < 8; mi++)
#pragma unroll
        for (int ni = 0; ni < 4; ni++)
#pragma unroll
            for (int rr = 0; rr < 4; rr++)
                C[(size_t)(crow0 + mi * 16 + rr) * N + ccol0 + ni * 16] = f2b(acc[mi][ni][rr]);
}

// ---------------- windowed 3-way gated attention (batch-local, fused output) ----------
__device__ __forceinline__ float wave_sum(float v) {
#pragma unroll
    for (int off = 32; off > 0; off >>= 1) v += __shfl_xor(v, off, 64);
    return v;
}

__global__ __launch_bounds__(256) void attn_k(const unsigned short* __restrict__ Q,
                                              const unsigned short* __restrict__ KV,
                                              const int* __restrict__ adv_ids,
                                              const int* __restrict__ ptr_ids,
                                              const float* __restrict__ council,
                                              const float* __restrict__ gain_p,
                                              float* __restrict__ out) {
    const int wave = threadIdx.x >> 6, lane = threadIdx.x & 63;
    const int t = blockIdx.x * 4 + wave;

    const int p = ptr_ids[t];
    int idx[3];
#pragma unroll
    for (int w = 0; w < 3; w++) {
        int v = p + w;
        idx[w] = v < (LL - 1) ? v : (LL - 1);
        if (idx[w] < 0) idx[w] = 0;
    }
    const int rel = adv_ids[idx[0]];

    const unsigned short* qrow = Q + (size_t)t * 2048 + lane * 16;
    us8v qj0 = *reinterpret_cast<const us8v*>(qrow);
    us8v qj1 = *reinterpret_cast<const us8v*>(qrow + 8);
    us8v qi0 = *reinterpret_cast<const us8v*>(qrow + 1024);
    us8v qi1 = *reinterpret_cast<const us8v*>(qrow + 1032);

    float sj[3], si[3];
    us8v vj[3][2], vi[3][2];
#pragma unroll
    for (int w = 0; w < 3; w++) {
        const unsigned short* kvrow = KV + (size_t)idx[w] * 4096 + lane * 16;
        us8v kj0 = *reinterpret_cast<const us8v*>(kvrow);
        us8v kj1 = *reinterpret_cast<const us8v*>(kvrow + 8);
        vj[w][0] = *reinterpret_cast<const us8v*>(kvrow + 1024);
        vj[w][1] = *reinterpret_cast<const us8v*>(kvrow + 1032);
        us8v ki0 = *reinterpret_cast<const us8v*>(kvrow + 2048);
        us8v ki1 = *reinterpret_cast<const us8v*>(kvrow + 2056);
        vi[w][0] = *reinterpret_cast<const us8v*>(kvrow + 3072);
        vi[w][1] = *reinterpret_cast<const us8v*>(kvrow + 3080);

        float dj = 0.f, di = 0.f;
#pragma unroll
        for (int e = 0; e < 8; e++) {
            dj += b2f(qj0[e]) * b2f(kj0[e]);
            dj += b2f(qj1[e]) * b2f(kj1[e]);
            di += b2f(qi0[e]) * b2f(ki0[e]);
            di += b2f(qi1[e]) * b2f(ki1[e]);
        }
        sj[w] = wave_sum(dj) * 0.03125f;
        si[w] = wave_sum(di) * 0.03125f;
    }

    const float l1 = sj[1], l2 = sj[2];
    float lf;
    switch (rel) {
        case 0: lf = l1 + l2; break;
        case 1: lf = fmaxf(l1, l2); break;
        case 2: lf = -l1; break;
        case 3: lf = fmaxf(-l1, l2); break;
        case 4: lf = fabsf(l1 - l2); break;
        default: lf = sj[0]; break;
    }

    float mj = fmaxf(lf, fmaxf(l1, l2));
    float ej0 = expf(lf - mj), ej1 = expf(l1 - mj), ej2 = expf(l2 - mj);
    float invj = 1.0f / (ej0 + ej1 + ej2);
    float aj0 = ej0 * invj, aj1 = ej1 * invj, aj2 = ej2 * invj;

    float mi2 = fmaxf(si[0], fmaxf(si[1], si[2]));
    float ei0 = expf(si[0] - mi2), ei1 = expf(si[1] - mi2), ei2 = expf(si[2] - mi2);
    float invi = 1.0f / (ei0 + ei1 + ei2);
    float ai0 = ei0 * invi, ai1 = ei1 * invi, ai2 = ei2 * invi;

    float c0 = council[0], c1 = council[1];
    float cm = fmaxf(c0, c1);
    float w0 = expf(c0 - cm), w1 = expf(c1 - cm);
    float wsum = 1.0f / (w0 + w1);
    w0 *= wsum; w1 *= wsum;
    const float g = *gain_p;

    float* dst = out + (size_t)t * 1024 + lane * 16;
#pragma unroll
    for (int h = 0; h < 2; h++) {
        float4 o0, o1;
        float* op[2] = {&o0.x, &o1.x};
#pragma unroll
        for (int e = 0; e < 8; e++) {
            float cj = aj0 * b2f(vj[0][h][e]) + aj1 * b2f(vj[1][h][e]) + aj2 * b2f(vj[2][h][e]);
            float ci = ai0 * b2f(vi[0][h][e]) + ai1 * b2f(vi[1][h][e]) + ai2 * b2f(vi[2][h][e]);
            op[e >> 2][e & 3] = (w0 * cj + w1 * ci) * g;
        }
        reinterpret_cast<float4*>(dst + h * 8)[0] = o0;
        reinterpret_cast<float4*>(dst + h * 8)[1] = o1;
    }
}

// ---------------- launch ----------------
extern "C" void kernel_launch(void* const* d_in, const int* in_sizes, int n_in,
                              void* d_out, int out_size, void* d_ws, size_t ws_size,
                              hipStream_t stream) {
    const float* hs      = (const float*)d_in[0];
    const float* adv     = (const float*)d_in[1];
    const int*   adv_ids = (const int*)d_in[2];
    const int*   ptr_ids = (const int*)d_in[3];
    const float* Wqj = (const float*)d_in[4];
    const float* Wkj = (const float*)d_in[5];
    const float* Wvj = (const float*)d_in[6];
    const float* Wqi = (const float*)d_in[7];
    const float* Wki = (const float*)d_in[8];
    const float* Wvi = (const float*)d_in[9];
    const float* Wout = (const float*)d_in[10];
    const float* gain = (const float*)d_in[11];
    const float* council = (const float*)d_in[12];
    float* out = (float*)d_out;

    const size_t WN  = (size_t)HH * HH;
    const size_t NHb = (size_t)TT * HH;
    dim3 blk(256);

    auto cvt = [&](const float* s, unsigned short* d, size_t n) {
        int n4 = (int)(n / 4);
        cvt_f32_bf16_k<<<dim3(n4 / 256), blk, 0, stream>>>((const float4*)s, (ushort4*)d, n4);
    };

    // ---- weight buffers: 18 MB ----
    char* ws = (char*)d_ws;
    unsigned short* Wq    = (unsigned short*)ws;  ws += WN * 2 * 2;   // [2048][1024]
    unsigned short* Wkv   = (unsigned short*)ws;  ws += WN * 4 * 2;   // [kj|vj2|ki|vi2][1024]
    unsigned short* WoutB = (unsigned short*)ws;  ws += WN * 2;
    unsigned short* WvjT  = (unsigned short*)ws;  ws += WN * 2;
    unsigned short* WviT  = (unsigned short*)ws;  ws += WN * 2;

    cvt(Wqj, Wq, WN);
    cvt(Wqi, Wq + WN, WN);
    cvt(Wkj, Wkv, WN);
    cvt(Wki, Wkv + 2 * WN, WN);
    cvt(Wout, WoutB, WN);
    transp_cvt_k<<<dim3(32, 32), blk, 0, stream>>>(Wvj, WvjT);
    transp_cvt_k<<<dim3(32, 32), blk, 0, stream>>>(Wvi, WviT);
    // fold Wout into V projections
    gemm_bt<<<dim3(8, 8), blk, 0, stream>>>(WoutB, WvjT, Wkv + WN, HH, HH, HH);
    gemm_bt<<<dim3(8, 8), blk, 0, stream>>>(WoutB, WviT, Wkv + 3 * WN, HH, HH, HH);

    const size_t full_need = (size_t)(18 * 1024 * 1024) + (NHb * BB) * 2
                           + (size_t)16384 * 2048 * 2 + (size_t)16384 * 4096 * 2;

    if (ws_size >= full_need) {
        unsigned short* advb = (unsigned short*)ws;  ws += NHb * BB * 2;
        unsigned short* Qb   = (unsigned short*)ws;  ws += (size_t)16384 * 2048 * 2;
        unsigned short* KVb  = (unsigned short*)ws;
        unsigned short* hsb  = KVb;                   // aliased; consumed before KVb written

        cvt(hs, hsb, NHb * BB);
        cvt(adv, advb, NHb * BB);
        gemm256<<<dim3(8 * 64), dim3(512), 0, stream>>>(hsb, Wq, Qb, 16384, 2048, 1024, 8);
        gemm256<<<dim3(16 * 64), dim3(512), 0, stream>>>(advb, Wkv, KVb, 16384, 4096, 1024, 16);
        for (int b = 0; b < BB; b++)
            attn_k<<<dim3(TT / 4), blk, 0, stream>>>(Qb + (size_t)b * TT * 2048,
                                                     KVb + (size_t)b * LL * 4096,
                                                     adv_ids + b * LL, ptr_ids + b * TT,
                                                     council, gain, out + (size_t)b * NHb);
    } else {
        unsigned short* advb = (unsigned short*)ws;  ws += NHb * 2;
        unsigned short* Qb   = (unsigned short*)ws;  ws += (size_t)TT * 2048 * 2;
        unsigned short* KVb  = (unsigned short*)ws;
        unsigned short* hsb  = KVb;                   // aliased

        for (int b = 0; b < BB; b++) {
            cvt(hs + (size_t)b * NHb, hsb, NHb);
            cvt(adv + (size_t)b * NHb, advb, NHb);
            gemm256<<<dim3(8 * 16), dim3(512), 0, stream>>>(hsb, Wq, Qb, TT, 2048, 1024, 8);
            gemm256<<<dim3(16 * 16), dim3(512), 0, stream>>>(advb, Wkv, KVb, LL, 4096, 1024, 16);
            attn_k<<<dim3(TT / 4), blk, 0, stream>>>(Qb, KVb, adv_ids + b * LL,
                                                     ptr_ids + b * TT, council, gain,
                                                     out + (size_t)b * NHb);
        }
    }
}

// Round 5
// 377.716 us; speedup vs baseline: 1.5533x; 1.0630x over previous
//
#include <hip/hip_runtime.h>
#include <hip/hip_bf16.h>
#include <stdint.h>

// Problem constants: B=4, T=4096, L=4096, H=1024
#define BB 4
#define TT 4096
#define LL 4096
#define HH 1024

typedef __bf16 bf16x8 __attribute__((ext_vector_type(8)));
typedef float f32x4 __attribute__((ext_vector_type(4)));
typedef unsigned short us8v __attribute__((ext_vector_type(8)));
typedef unsigned short us;

// f32 -> bf16 bits, round-to-nearest-even
__device__ __forceinline__ unsigned short f2b(float f) {
    unsigned u = __builtin_bit_cast(unsigned, f);
    unsigned r = (u + 0x7FFFu + ((u >> 16) & 1u)) >> 16;
    return (unsigned short)r;
}
__device__ __forceinline__ float b2f(unsigned short u) {
    unsigned x = ((unsigned)u) << 16;
    return __builtin_bit_cast(float, x);
}

// async global->LDS, 16B/lane. LDS base wave-uniform (HW adds lane*16).
__device__ __forceinline__ void gload_lds16(const void* g, void* l) {
    __builtin_amdgcn_global_load_lds(
        (const __attribute__((address_space(1))) void*)(uintptr_t)g,
        (__attribute__((address_space(3))) void*)(uintptr_t)l,
        16, 0, 0);
}

// ---------------- f32 -> bf16 conversion ----------------
__global__ __launch_bounds__(256) void cvt_f32_bf16_k(const float4* __restrict__ src,
                                                      ushort4* __restrict__ dst, int n4) {
    int i = blockIdx.x * 256 + threadIdx.x;
    if (i >= n4) return;
    float4 v = src[i];
    ushort4 o;
    o.x = f2b(v.x); o.y = f2b(v.y); o.z = f2b(v.z); o.w = f2b(v.w);
    dst[i] = o;
}

// ---------------- f32 [1024][1024] -> bf16 transpose ----------------
__global__ __launch_bounds__(256) void transp_cvt_k(const float* __restrict__ src,
                                                    unsigned short* __restrict__ dst) {
    __shared__ float tile[32][33];
    const int lx = threadIdx.x & 31, ly = threadIdx.x >> 5;
    const int R = blockIdx.y * 32, C = blockIdx.x * 32;
#pragma unroll
    for (int rr = 0; rr < 4; rr++)
        tile[ly + rr * 8][lx] = src[(size_t)(R + ly + rr * 8) * HH + C + lx];
    __syncthreads();
#pragma unroll
    for (int rr = 0; rr < 4; rr++)
        dst[(size_t)(C + ly + rr * 8) * HH + R + lx] = f2b(tile[lx][ly + rr * 8]);
}

// ---------------- fold GEMM: both V-weight folds in one launch -----------------------
// A[1024][1024] (WoutB), Bw[2048][1024] (WvjT|WviT). C split: col<1024 -> dst1, else dst2.
__global__ __launch_bounds__(256) void gemm_fold(const unsigned short* __restrict__ A,
                                                 const unsigned short* __restrict__ Bw,
                                                 unsigned short* __restrict__ dst1,
                                                 unsigned short* __restrict__ dst2) {
    const int K = 1024;
    __shared__ unsigned short ldsA[128 * 64];
    __shared__ unsigned short ldsB[128 * 64];

    const int tid = threadIdx.x;
    const int wave = tid >> 6, lane = tid & 63;
    const int m0 = blockIdx.y * 128, n0 = blockIdx.x * 128;
    const int wr = wave >> 1, wc = wave & 1;

    f32x4 acc[4][4];
#pragma unroll
    for (int m = 0; m < 4; m++)
#pragma unroll
        for (int n = 0; n < 4; n++) acc[m][n] = (f32x4)(0.0f);

    const unsigned short* Ab = A + (size_t)m0 * K;
    const unsigned short* Bb = Bw + (size_t)n0 * K;
    const int rbase = tid >> 3;
    const int col0 = (((tid & 7) ^ (rbase & 7)) << 3);

    for (int k0 = 0; k0 < K; k0 += 64) {
#pragma unroll
        for (int r = 0; r < 4; r++) {
            const int row = r * 32 + rbase;
            gload_lds16(Ab + (size_t)row * K + k0 + col0, &ldsA[r * 2048 + wave * 512]);
            gload_lds16(Bb + (size_t)row * K + k0 + col0, &ldsB[r * 2048 + wave * 512]);
        }
        __syncthreads();

        const int lr = lane & 15, hi = lane >> 4;
        const int sw = (lr & 7) << 4;
        const int c0 = ((hi * 16) ^ sw) >> 1;
        const int c1 = ((64 + hi * 16) ^ sw) >> 1;
        bf16x8 a0[4], a1[4], b0[4], b1[4];
#pragma unroll
        for (int m = 0; m < 4; m++) {
            const int row = (wr * 64 + m * 16 + lr) * 64;
            a0[m] = *reinterpret_cast<const bf16x8*>(&ldsA[row + c0]);
            a1[m] = *reinterpret_cast<const bf16x8*>(&ldsA[row + c1]);
        }
#pragma unroll
        for (int n = 0; n < 4; n++) {
            const int row = (wc * 64 + n * 16 + lr) * 64;
            b0[n] = *reinterpret_cast<const bf16x8*>(&ldsB[row + c0]);
            b1[n] = *reinterpret_cast<const bf16x8*>(&ldsB[row + c1]);
        }
#pragma unroll
        for (int m = 0; m < 4; m++)
#pragma unroll
            for (int n = 0; n < 4; n++)
                acc[m][n] = __builtin_amdgcn_mfma_f32_16x16x32_bf16(a0[m], b0[n], acc[m][n], 0, 0, 0);
#pragma unroll
        for (int m = 0; m < 4; m++)
#pragma unroll
            for (int n = 0; n < 4; n++)
                acc[m][n] = __builtin_amdgcn_mfma_f32_16x16x32_bf16(a1[m], b1[n], acc[m][n], 0, 0, 0);
        __syncthreads();
    }

    const int cc = lane & 15, cr = (lane >> 4) * 4;
#pragma unroll
    for (int m = 0; m < 4; m++)
#pragma unroll
        for (int n = 0; n < 4; n++)
#pragma unroll
            for (int r = 0; r < 4; r++) {
                const int row = m0 + wr * 64 + m * 16 + cr + r;
                const int col = n0 + wc * 64 + n * 16 + cc;
                unsigned short* base = (col < 1024) ? dst1 : dst2;
                base[(size_t)row * 1024 + (col & 1023)] = f2b(acc[m][n][r]);
            }
}

// ---------------- 256x256 GEMM, relaxed 2-half pipeline ------------------------------
// 8 waves (2M x 4N), per-wave 128x64 = 8x4 frags of 16x16x32. BK=64 as two kk-chunks
// of 32; chunk [256r][32k] stored as 2-row/128B units, 8-slot XOR swizzle. Double-
// buffered (128 KiB). Counted vmcnt(4) (never 0 in loop). NO pre-MFMA barrier, NO
// lgkm full drain: compiler emits counted lgkmcnt so MFMA starts as soon as its own
// frags land; reads drain under the 32-MFMA cluster. One BAR + sched_barrier(0) pin
// per half, placed at the only cross-wave buffer hazards (after each VMW4).
__device__ __forceinline__ void mfma32(const bf16x8 a[8], const bf16x8 b[4], f32x4 acc[8][4]) {
    __builtin_amdgcn_s_setprio(1);
#pragma unroll
    for (int m = 0; m < 8; m++)
#pragma unroll
        for (int n = 0; n < 4; n++)
            acc[m][n] = __builtin_amdgcn_mfma_f32_16x16x32_bf16(a[m], b[n], acc[m][n], 0, 0, 0);
    __builtin_amdgcn_s_setprio(0);
}

#define STAGE2(chunk, src, kcol) \
    { _Pragma("unroll") for (int r_ = 0; r_ < 2; r_++) \
        gload_lds16((src) + (size_t)srow[r_] * K + (kcol) + scol[r_], (chunk) + r_ * 4096 + wave * 512); }

#define RD_A8(cA) \
    { _Pragma("unroll") for (int m_ = 0; m_ < 8; m_++) \
        a[m_] = *reinterpret_cast<const bf16x8*>((cA) + offA + m_ * 512); }

#define RD_B4(cB) \
    { _Pragma("unroll") for (int n_ = 0; n_ < 4; n_++) \
        b[n_] = *reinterpret_cast<const bf16x8*>((cB) + offB + n_ * 512); }

#define BAR __builtin_amdgcn_s_barrier()
#define SB0 __builtin_amdgcn_sched_barrier(0)
#define VMW4 asm volatile("s_waitcnt vmcnt(4)" ::: "memory")
#define VMW0 asm volatile("s_waitcnt vmcnt(0)" ::: "memory")
#define NOWAIT

// One half-K-tile: read frags (compiler-scheduled lgkm), stage next-tile chunks,
// 32 MFMA, counted-vmcnt wait, single barrier pin.
#define HALF(cA, cB, nA, nB, kn, STG, WAIT)                  \
  {                                                           \
    RD_A8(cA); RD_B4(cB);                                     \
    if (STG) { STAGE2(nA, Ablk, (kn)); STAGE2(nB, Bblk, (kn)); } \
    mfma32(a, b, acc);                                        \
    WAIT;                                                     \
    BAR; SB0;                                                 \
  }

__global__ __launch_bounds__(512, 2) void gemm256(const us* __restrict__ A,
                                                  const us* __restrict__ Bw,
                                                  us* __restrict__ C,
                                                  int M, int N, int K, int gx) {
    __shared__ us lds[65536];   // 128 KB

    const int nwg = gridDim.x;
    const int bid = blockIdx.x;
    const int swz = (bid & 7) * (nwg >> 3) + (bid >> 3);   // grids are multiples of 8
    const int bx = swz % gx, by = swz / gx;
    const int m0 = by * 256, n0 = bx * 256;

    const int tid = threadIdx.x;
    const int wave = tid >> 6, lane = tid & 63;
    const int wr = wave >> 2, wc = wave & 3;
    const int lr = lane & 15, hi = lane >> 4;

    // stage source mapping (inverse swizzle, rule #21): chunk byte = r*8192 + tid*16
    int srow[2], scol[2];
#pragma unroll
    for (int r = 0; r < 2; r++) {
        const int q = r * 64 + (tid >> 3);
        const int s = (tid & 7) ^ (q & 7);
        srow[r] = 2 * q + (s >> 2);
        scol[r] = (s & 3) * 8;
    }
    const us* Ablk = A + (size_t)m0 * K;
    const us* Bblk = Bw + (size_t)n0 * K;

    // ds_read offsets (elems); frag i at off + i*512 (swizzle frag-invariant)
    const int rA = wr * 128 + lr;
    const int offA = (rA >> 1) * 64 + (((((rA & 1) << 2) + hi) ^ ((rA >> 1) & 7)) << 3);
    const int rB = wc * 64 + lr;
    const int offB = (rB >> 1) * 64 + (((((rB & 1) << 2) + hi) ^ ((rB >> 1) & 7)) << 3);

    f32x4 acc[8][4];
#pragma unroll
    for (int m = 0; m < 8; m++)
#pragma unroll
        for (int n = 0; n < 4; n++) acc[m][n] = (f32x4)(0.0f);

    us* cA0 = lds;          us* cA1 = lds + 8192;
    us* cB0 = lds + 16384;  us* cB1 = lds + 24576;
    us* nA0 = lds + 32768;  us* nA1 = lds + 40960;
    us* nB0 = lds + 49152;  us* nB1 = lds + 57344;

    bf16x8 a[8], b[4];

    // prologue: stage tile 0 (A0,B0 oldest; A1,B1 newest)
    STAGE2(cA0, Ablk, 0);
    STAGE2(cB0, Bblk, 0);
    STAGE2(cA1, Ablk, 32);
    STAGE2(cB1, Bblk, 32);
    VMW4;            // drains A0,B0
    BAR; SB0;

    const int NT = K >> 6;
    for (int t = 0; t < NT - 1; ++t) {
        const int kn = (t + 1) << 6;
        // half 0: VMW4 drains prev nA1,nB1 (read next as cA1/cB1)
        HALF(cA0, cB0, nA0, nB0, kn, true, VMW4);
        // half 1: VMW4 drains this tile's nA0,nB0 (read next as cA0/cB0)
        HALF(cA1, cB1, nA1, nB1, kn + 32, true, VMW4);
        us* s0 = cA0; cA0 = nA0; nA0 = s0;
        us* s1 = cA1; cA1 = nA1; nA1 = s1;
        us* s2 = cB0; cB0 = nB0; nB0 = s2;
        us* s3 = cB1; cB1 = nB1; nB1 = s3;
    }
    // last tile: no staging; drain remaining (cA1,cB1) before half 1
    HALF(cA0, cB0, nA0, nB0, 0, false, VMW0);
    HALF(cA1, cB1, nA1, nB1, 0, false, NOWAIT);

    // C write: col = lane&15, row = hi*4 + reg
    const int crow0 = m0 + wr * 128 + hi * 4;
    const int ccol0 = n0 + wc * 64 + lr;
#pragma unroll
    for (int mi = 0; mi < 8; mi++)
#pragma unroll
        for (int ni = 0; ni < 4; ni++)
#pragma unroll
            for (int rr = 0; rr < 4; rr++)
                C[(size_t)(crow0 + mi * 16 + rr) * N + ccol0 + ni * 16] = f2b(acc[mi][ni][rr]);
}

// ---------------- windowed 3-way gated attention (batch-local, fused output) ----------
__device__ __forceinline__ float wave_sum(float v) {
#pragma unroll
    for (int off = 32; off > 0; off >>= 1) v += __shfl_xor(v, off, 64);
    return v;
}

__global__ __launch_bounds__(256) void attn_k(const unsigned short* __restrict__ Q,
                                              const unsigned short* __restrict__ KV,
                                              const int* __restrict__ adv_ids,
                                              const int* __restrict__ ptr_ids,
                                              const float* __restrict__ council,
                                              const float* __restrict__ gain_p,
                                              float* __restrict__ out) {
    const int wave = threadIdx.x >> 6, lane = threadIdx.x & 63;
    const int t = blockIdx.x * 4 + wave;

    const int p = ptr_ids[t];
    int idx[3];
#pragma unroll
    for (int w = 0; w < 3; w++) {
        int v = p + w;
        idx[w] = v < (LL - 1) ? v : (LL - 1);
        if (idx[w] < 0) idx[w] = 0;
    }
    const int rel = adv_ids[idx[0]];

    const unsigned short* qrow = Q + (size_t)t * 2048 + lane * 16;
    us8v qj0 = *reinterpret_cast<const us8v*>(qrow);
    us8v qj1 = *reinterpret_cast<const us8v*>(qrow + 8);
    us8v qi0 = *reinterpret_cast<const us8v*>(qrow + 1024);
    us8v qi1 = *reinterpret_cast<const us8v*>(qrow + 1032);

    float sj[3], si[3];
    us8v vj[3][2], vi[3][2];
#pragma unroll
    for (int w = 0; w < 3; w++) {
        const unsigned short* kvrow = KV + (size_t)idx[w] * 4096 + lane * 16;
        us8v kj0 = *reinterpret_cast<const us8v*>(kvrow);
        us8v kj1 = *reinterpret_cast<const us8v*>(kvrow + 8);
        vj[w][0] = *reinterpret_cast<const us8v*>(kvrow + 1024);
        vj[w][1] = *reinterpret_cast<const us8v*>(kvrow + 1032);
        us8v ki0 = *reinterpret_cast<const us8v*>(kvrow + 2048);
        us8v ki1 = *reinterpret_cast<const us8v*>(kvrow + 2056);
        vi[w][0] = *reinterpret_cast<const us8v*>(kvrow + 3072);
        vi[w][1] = *reinterpret_cast<const us8v*>(kvrow + 3080);

        float dj = 0.f, di = 0.f;
#pragma unroll
        for (int e = 0; e < 8; e++) {
            dj += b2f(qj0[e]) * b2f(kj0[e]);
            dj += b2f(qj1[e]) * b2f(kj1[e]);
            di += b2f(qi0[e]) * b2f(ki0[e]);
            di += b2f(qi1[e]) * b2f(ki1[e]);
        }
        sj[w] = wave_sum(dj) * 0.03125f;
        si[w] = wave_sum(di) * 0.03125f;
    }

    const float l1 = sj[1], l2 = sj[2];
    float lf;
    switch (rel) {
        case 0: lf = l1 + l2; break;
        case 1: lf = fmaxf(l1, l2); break;
        case 2: lf = -l1; break;
        case 3: lf = fmaxf(-l1, l2); break;
        case 4: lf = fabsf(l1 - l2); break;
        default: lf = sj[0]; break;
    }

    float mj = fmaxf(lf, fmaxf(l1, l2));
    float ej0 = expf(lf - mj), ej1 = expf(l1 - mj), ej2 = expf(l2 - mj);
    float invj = 1.0f / (ej0 + ej1 + ej2);
    float aj0 = ej0 * invj, aj1 = ej1 * invj, aj2 = ej2 * invj;

    float mi2 = fmaxf(si[0], fmaxf(si[1], si[2]));
    float ei0 = expf(si[0] - mi2), ei1 = expf(si[1] - mi2), ei2 = expf(si[2] - mi2);
    float invi = 1.0f / (ei0 + ei1 + ei2);
    float ai0 = ei0 * invi, ai1 = ei1 * invi, ai2 = ei2 * invi;

    float c0 = council[0], c1 = council[1];
    float cm = fmaxf(c0, c1);
    float w0 = expf(c0 - cm), w1 = expf(c1 - cm);
    float wsum = 1.0f / (w0 + w1);
    w0 *= wsum; w1 *= wsum;
    const float g = *gain_p;

    float* dst = out + (size_t)t * 1024 + lane * 16;
#pragma unroll
    for (int h = 0; h < 2; h++) {
        float4 o0, o1;
        float* op[2] = {&o0.x, &o1.x};
#pragma unroll
        for (int e = 0; e < 8; e++) {
            float cj = aj0 * b2f(vj[0][h][e]) + aj1 * b2f(vj[1][h][e]) + aj2 * b2f(vj[2][h][e]);
            float ci = ai0 * b2f(vi[0][h][e]) + ai1 * b2f(vi[1][h][e]) + ai2 * b2f(vi[2][h][e]);
            op[e >> 2][e & 3] = (w0 * cj + w1 * ci) * g;
        }
        reinterpret_cast<float4*>(dst + h * 8)[0] = o0;
        reinterpret_cast<float4*>(dst + h * 8)[1] = o1;
    }
}

// ---------------- launch ----------------
extern "C" void kernel_launch(void* const* d_in, const int* in_sizes, int n_in,
                              void* d_out, int out_size, void* d_ws, size_t ws_size,
                              hipStream_t stream) {
    const float* hs      = (const float*)d_in[0];
    const float* adv     = (const float*)d_in[1];
    const int*   adv_ids = (const int*)d_in[2];
    const int*   ptr_ids = (const int*)d_in[3];
    const float* Wqj = (const float*)d_in[4];
    const float* Wkj = (const float*)d_in[5];
    const float* Wvj = (const float*)d_in[6];
    const float* Wqi = (const float*)d_in[7];
    const float* Wki = (const float*)d_in[8];
    const float* Wvi = (const float*)d_in[9];
    const float* Wout = (const float*)d_in[10];
    const float* gain = (const float*)d_in[11];
    const float* council = (const float*)d_in[12];
    float* out = (float*)d_out;

    const size_t WN  = (size_t)HH * HH;
    const size_t NHb = (size_t)TT * HH;
    dim3 blk(256);

    auto cvt = [&](const float* s, unsigned short* d, size_t n) {
        int n4 = (int)(n / 4);
        cvt_f32_bf16_k<<<dim3(n4 / 256), blk, 0, stream>>>((const float4*)s, (ushort4*)d, n4);
    };

    // ---- weight buffers: 18 MB ----
    char* ws = (char*)d_ws;
    unsigned short* Wq    = (unsigned short*)ws;  ws += WN * 2 * 2;   // [2048][1024]
    unsigned short* Wkv   = (unsigned short*)ws;  ws += WN * 4 * 2;   // [kj|vj2|ki|vi2][1024]
    unsigned short* WoutB = (unsigned short*)ws;  ws += WN * 2;
    unsigned short* WvT   = (unsigned short*)ws;  ws += WN * 2 * 2;   // [WvjT | WviT]

    cvt(Wqj, Wq, WN);
    cvt(Wqi, Wq + WN, WN);
    cvt(Wkj, Wkv, WN);
    cvt(Wki, Wkv + 2 * WN, WN);
    cvt(Wout, WoutB, WN);
    transp_cvt_k<<<dim3(32, 32), blk, 0, stream>>>(Wvj, WvT);
    transp_cvt_k<<<dim3(32, 32), blk, 0, stream>>>(Wvi, WvT + WN);
    // fold Wout into both V projections in one launch
    gemm_fold<<<dim3(16, 8), blk, 0, stream>>>(WoutB, WvT, Wkv + WN, Wkv + 3 * WN);

    const size_t full_need = (size_t)(18 * 1024 * 1024) + (NHb * BB) * 2
                           + (size_t)16384 * 2048 * 2 + (size_t)16384 * 4096 * 2;

    if (ws_size >= full_need) {
        unsigned short* advb = (unsigned short*)ws;  ws += NHb * BB * 2;
        unsigned short* Qb   = (unsigned short*)ws;  ws += (size_t)16384 * 2048 * 2;
        unsigned short* KVb  = (unsigned short*)ws;
        unsigned short* hsb  = KVb;                   // aliased; consumed before KVb written

        cvt(hs, hsb, NHb * BB);
        cvt(adv, advb, NHb * BB);
        gemm256<<<dim3(8 * 64), dim3(512), 0, stream>>>(hsb, Wq, Qb, 16384, 2048, 1024, 8);
        gemm256<<<dim3(16 * 64), dim3(512), 0, stream>>>(advb, Wkv, KVb, 16384, 4096, 1024, 16);
        for (int b = 0; b < BB; b++)
            attn_k<<<dim3(TT / 4), blk, 0, stream>>>(Qb + (size_t)b * TT * 2048,
                                                     KVb + (size_t)b * LL * 4096,
                                                     adv_ids + b * LL, ptr_ids + b * TT,
                                                     council, gain, out + (size_t)b * NHb);
    } else {
        unsigned short* advb = (unsigned short*)ws;  ws += NHb * 2;
        unsigned short* Qb   = (unsigned short*)ws;  ws += (size_t)TT * 2048 * 2;
        unsigned short* KVb  = (unsigned short*)ws;
        unsigned short* hsb  = KVb;                   // aliased

        for (int b = 0; b < BB; b++) {
            cvt(hs + (size_t)b * NHb, hsb, NHb);
            cvt(adv + (size_t)b * NHb, advb, NHb);
            gemm256<<<dim3(8 * 16), dim3(512), 0, stream>>>(hsb, Wq, Qb, TT, 2048, 1024, 8);
            gemm256<<<dim3(16 * 16), dim3(512), 0, stream>>>(advb, Wkv, KVb, LL, 4096, 1024, 16);
            attn_k<<<dim3(TT / 4), blk, 0, stream>>>(Qb, KVb, adv_ids + b * LL,
                                                     ptr_ids + b * TT, council, gain,
                                                     out + (size_t)b * NHb);
        }
    }
}